// Round 1
// baseline (698.626 us; speedup 1.0000x reference)
//
#include <hip/hip_runtime.h>

#define BATCHN 256
#define TSTEPS 199          // MAX_STEP - 1
#define NQ     1000
#define NROWS  (BATCHN * TSTEPS)   // 50944

// ws layout (floats): [0..255] masked bce sum per batch, [256..511] masked row count per batch
__global__ void zero_ws_kernel(float* __restrict__ ws) {
    int i = threadIdx.x;
    if (i < 2 * BATCHN) ws[i] = 0.0f;
}

__global__ __launch_bounds__(256) void main_kernel(
    const float* __restrict__ pred,
    const float* __restrict__ batch,
    float* __restrict__ out,
    float* __restrict__ ws)
{
    const int r = blockIdx.x;              // row index 0..NROWS-1
    const int b = r / TSTEPS;
    const int t = r - b * TSTEPS;
    const int i = threadIdx.x;

    const float4* p4 = (const float4*)(pred + (size_t)r * NQ);
    const float4* g4 = (const float4*)(batch + ((size_t)b * 200 + t + 1) * NQ);

    float4 p = make_float4(0.f, 0.f, 0.f, 0.f);
    float4 g = make_float4(0.f, 0.f, 0.f, 0.f);
    if (i < 250) { p = p4[i]; g = g4[i]; }

    float s = 0.0f;
    int any = 0;
    if (i < 250) {
        float pe[4] = {p.x, p.y, p.z, p.w};
        float ge[4] = {g.x, g.y, g.z, g.w};
        #pragma unroll
        for (int k = 0; k < 4; ++k) {
            any |= (ge[k] == 1.0f);
            float lp = fmaxf(__logf(pe[k]),        -100.0f);
            float l1 = fmaxf(__logf(1.0f - pe[k]), -100.0f);
            // bce = -(g*lp + (1-g)*l1) = -(l1 + g*(lp - l1))
            s -= l1 + ge[k] * (lp - l1);
        }
    }

    // wave (64) reduction
    #pragma unroll
    for (int off = 32; off > 0; off >>= 1) {
        s   += __shfl_down(s, off);
        any |= __shfl_down(any, off);
    }

    __shared__ float ssum[4];
    __shared__ int   sany[4];
    const int lane = i & 63, wid = i >> 6;
    if (lane == 0) { ssum[wid] = s; sany[wid] = any; }
    __syncthreads();

    __shared__ float bsum;
    __shared__ int   bany;
    if (i == 0) {
        bsum = ssum[0] + ssum[1] + ssum[2] + ssum[3];
        bany = sany[0] | sany[1] | sany[2] | sany[3];
    }
    __syncthreads();

    const float m = bany ? 1.0f : 0.0f;

    float* out_pred = out + 1;
    float* out_gt   = out + 1 + (size_t)NROWS * NQ;
    float* out_mask = out + 1 + 2 * (size_t)NROWS * NQ;

    if (i < 250) {
        size_t o = (size_t)r * NQ + 4 * (size_t)i;
        out_pred[o + 0] = p.x * m;
        out_pred[o + 1] = p.y * m;
        out_pred[o + 2] = p.z * m;
        out_pred[o + 3] = p.w * m;
        out_gt[o + 0] = g.x * m;
        out_gt[o + 1] = g.y * m;
        out_gt[o + 2] = g.z * m;
        out_gt[o + 3] = g.w * m;
    }
    if (i == 0) {
        out_mask[r] = m;
        if (bany) {
            atomicAdd(&ws[b], bsum);
            atomicAdd(&ws[BATCHN + b], 1.0f);
        }
    }
}

__global__ __launch_bounds__(256) void final_kernel(
    float* __restrict__ out, const float* __restrict__ ws)
{
    const int b = threadIdx.x;  // 0..255 (one per batch element)
    // cnt >= 1 guaranteed: batch[:,1,0] == 1 so t=0 row is always masked
    float per = ws[b] / (ws[BATCHN + b] * (float)NQ);

    #pragma unroll
    for (int off = 32; off > 0; off >>= 1) per += __shfl_down(per, off);

    __shared__ float ssum[4];
    const int lane = b & 63, wid = b >> 6;
    if (lane == 0) ssum[wid] = per;
    __syncthreads();
    if (b == 0) out[0] = ssum[0] + ssum[1] + ssum[2] + ssum[3];
}

extern "C" void kernel_launch(void* const* d_in, const int* in_sizes, int n_in,
                              void* d_out, int out_size, void* d_ws, size_t ws_size,
                              hipStream_t stream) {
    const float* pred  = (const float*)d_in[0];
    const float* batch = (const float*)d_in[1];
    float* out = (float*)d_out;
    float* ws  = (float*)d_ws;

    zero_ws_kernel<<<1, 512, 0, stream>>>(ws);
    main_kernel<<<NROWS, 256, 0, stream>>>(pred, batch, out, ws);
    final_kernel<<<1, 256, 0, stream>>>(out, ws);
}